// Round 1
// baseline (259.360 us; speedup 1.0000x reference)
//
#include <hip/hip_runtime.h>
#include <stdint.h>

#define HWP 784      // 28*28
#define NPOS 50176   // 64*784 positions

typedef int int4v  __attribute__((ext_vector_type(4)));
typedef int int16v __attribute__((ext_vector_type(16)));
using as1_cv = const __attribute__((address_space(1))) void;
using as3_v  = __attribute__((address_space(3))) void;

// ---------------- kernel 1: x NCHW fp32 -> x8 NHWC int8 (value - 128) ----------------
__global__ __launch_bounds__(256) void k_x_to_nhwc(const float* __restrict__ x,
                                                   int8_t* __restrict__ x8) {
    __shared__ __align__(16) int8_t tile[64][116];  // [c][hw], padded row -> conflict-free
    int b = blockIdx.x;                 // b = n*28 + hwt*4 + ct
    int ct = b & 3;
    int hwt = (b >> 2) % 7;
    int n = b / 28;
    int c0 = ct * 64, hw0 = hwt * 112;
    int tid = threadIdx.x;
#pragma unroll
    for (int k = 0; k < 28; ++k) {      // 64c x 112hw = 7168 elems
        int e = tid + k * 256;
        int c = e / 112, hh = e % 112;
        float v = x[((size_t)(n * 256 + c0 + c)) * HWP + hw0 + hh];
        tile[c][hh] = (int8_t)((int)v - 128);
    }
    __syncthreads();
    int cc = tid & 63;
    int pb = tid >> 6;
#pragma unroll
    for (int j = 0; j < 28; ++j) {
        int pi = pb + j * 4;
        x8[((size_t)(n * HWP + hw0 + pi)) * 256 + c0 + cc] = tile[cc][pi];
    }
}

// ---------------- kernel 2: weights OIHW fp32 -> fragment-major int8 ----------------
// layout byte index: ((((tap*4+kb)*2+s)*8 + g)*64 + lane)*16 + j
//   oc = g*32 + (lane&31); ic = kb*64 + s*32 + (lane>>5)*16 + j
__global__ __launch_bounds__(256) void k_w_prep(const float* __restrict__ w,
                                                int8_t* __restrict__ w8) {
    int o = (blockIdx.x * 256 + threadIdx.x) * 4;
#pragma unroll
    for (int u = 0; u < 4; ++u) {
        int oo = o + u;
        int j   = oo & 15;
        int l   = (oo >> 4) & 63;
        int g   = (oo >> 10) & 7;
        int s   = (oo >> 13) & 1;
        int kb  = (oo >> 14) & 3;
        int tap = oo >> 16;
        int oc = g * 32 + (l & 31);
        int k  = kb * 64 + s * 32 + (l >> 5) * 16 + j;
        w8[oo] = (int8_t)(int)w[(size_t)oc * 2304 + (size_t)k * 9 + tap];
    }
}

// ---------------- kernel 3: per-oc weight sums + pad-fill bytes (z_in - 128) -------
__global__ __launch_bounds__(256) void k_wsum_fill(const float* __restrict__ w,
        int* __restrict__ wsum, int8_t* __restrict__ fill,
        const float* __restrict__ z_in) {
    __shared__ int red[256];
    int oc = blockIdx.x;
    int tid = threadIdx.x;
    const float* base = w + (size_t)oc * 2304 + (size_t)tid * 9;
    int s = 0;
#pragma unroll
    for (int t = 0; t < 9; ++t) s += (int)base[t];
    red[tid] = s;
    __syncthreads();
    for (int st = 128; st > 0; st >>= 1) {
        if (tid < st) red[tid] += red[tid + st];
        __syncthreads();
    }
    if (tid == 0) wsum[oc] = red[0];
    if (oc == 0 && tid < 64) fill[tid] = (int8_t)((int)z_in[0] - 128);
}

// ---------------- kernel 4: quantized 3x3 conv as implicit GEMM (MFMA i8) ----------
// in8 NHWC i8 (value-128); out8 NHWC i8 (q-128). Block: 64 positions x 256 oc.
// K = 9 taps x 256 ic, stepped 64 at a time (36 steps). Wave w handles oc [w*64,w*64+64).
// Exactness: acc = sum_all g*w + (128 - z_in)*Wsum[oc], pad fill = z_in - 128.
__global__ __launch_bounds__(256) void k_qconv(const int8_t* __restrict__ in8,
        const int8_t* __restrict__ w8, const int* __restrict__ wsum,
        const int8_t* __restrict__ fill,
        const float* __restrict__ s_in_p, const float* __restrict__ s_w_p,
        const float* __restrict__ s_out_p, const float* __restrict__ z_in_p,
        const float* __restrict__ z_out_p, int8_t* __restrict__ out8) {
    __shared__ __align__(16) int8_t As[2][4096];   // [64 pos][64 ic], chunk-swizzled
    const int tid = threadIdx.x;
    const int lane = tid & 63;
    const int wv = tid >> 6;
    const int p0 = blockIdx.x * 64;

    // staging role: thread t covers (pos = t>>2, 16B chunk (t&3) xor-swizzled)
    const int sp = tid >> 2;
    const int slot = tid & 3;
    const int chunk = slot ^ ((sp >> 1) & 3);
    const int p = p0 + sp;
    const int hw = p % HWP;
    const int ph = hw / 28;
    const int pw = hw % 28;

    int16v acc[2][2];
#pragma unroll
    for (int mt = 0; mt < 2; ++mt)
#pragma unroll
        for (int nt = 0; nt < 2; ++nt)
#pragma unroll
            for (int r = 0; r < 16; ++r) acc[mt][nt][r] = 0;

    // A-fragment LDS offsets: row = mt*32+(lane&31), chunk c = s*2+(lane>>5), xor swizzle
    int aoff[2][2];
#pragma unroll
    for (int mt = 0; mt < 2; ++mt)
#pragma unroll
        for (int s = 0; s < 2; ++s) {
            int row = mt * 32 + (lane & 31);
            int c = s * 2 + (lane >> 5);
            aoff[mt][s] = row * 64 + (c ^ ((row >> 1) & 3)) * 16;
        }

    const int8_t* wlane = w8 + ((size_t)(wv * 2 * 64 + lane)) * 16;

    auto stage = [&](int step, int buf) {
        int tap = step >> 2;
        int kb = step & 3;
        int kh = tap / 3;
        int dh = kh - 1;
        int dw = tap - kh * 3 - 1;
        int hh = ph + dh, ww = pw + dw;
        const int8_t* src;
        if ((unsigned)hh < 28u && (unsigned)ww < 28u)
            src = in8 + (size_t)(p + dh * 28 + dw) * 256 + kb * 64 + chunk * 16;
        else
            src = fill + chunk * 16;
        __builtin_amdgcn_global_load_lds((as1_cv*)src, (as3_v*)&As[buf][tid * 16], 16, 0, 0);
    };

    stage(0, 0);
    __syncthreads();

    for (int step = 0; step < 36; ++step) {
        if (step < 35) stage(step + 1, (step + 1) & 1);   // overlaps compute of `step`
        const int8_t* wb = wlane + (size_t)step * 16384;  // (tap*4+kb)*2*8192
        int4v b0[2], b1[2], a0[2], a1[2];
#pragma unroll
        for (int nt = 0; nt < 2; ++nt) {
            b0[nt] = *(const int4v*)(wb + nt * 1024);          // k-sub 0
            b1[nt] = *(const int4v*)(wb + 8192 + nt * 1024);   // k-sub 1
        }
        const int8_t* ab = As[step & 1];
#pragma unroll
        for (int mt = 0; mt < 2; ++mt) {
            a0[mt] = *(const int4v*)(ab + aoff[mt][0]);
            a1[mt] = *(const int4v*)(ab + aoff[mt][1]);
        }
#pragma unroll
        for (int mt = 0; mt < 2; ++mt)
#pragma unroll
            for (int nt = 0; nt < 2; ++nt) {
                acc[mt][nt] = __builtin_amdgcn_mfma_i32_32x32x32_i8(a0[mt], b0[nt], acc[mt][nt], 0, 0, 0);
                acc[mt][nt] = __builtin_amdgcn_mfma_i32_32x32x32_i8(a1[mt], b1[nt], acc[mt][nt], 0, 0, 0);
            }
        __syncthreads();
    }

    // epilogue: requantize.  q = clip(rint(M*acc) + z_out, 0, 255); store q-128.
    const float Mf = s_in_p[0] * s_w_p[0] / s_out_p[0];
    const float zof = z_out_p[0];
    const int zoffi = 128 - (int)z_in_p[0];
#pragma unroll
    for (int nt = 0; nt < 2; ++nt) {
        int oc = wv * 64 + nt * 32 + (lane & 31);
        int corr = zoffi * wsum[oc];
#pragma unroll
        for (int mt = 0; mt < 2; ++mt) {
#pragma unroll
            for (int r = 0; r < 16; ++r) {
                int row = (r & 3) + 8 * (r >> 2) + 4 * (lane >> 5);  // 32x32 C/D layout
                int pos = p0 + mt * 32 + row;
                float q = rintf(Mf * (float)(acc[mt][nt][r] + corr)) + zof;
                q = fminf(fmaxf(q, 0.0f), 255.0f);
                out8[(size_t)pos * 256 + oc] = (int8_t)((int)q - 128);
            }
        }
    }
}

// ---------------- kernel 5: residual qadd, NHWC i8 x2 -> NCHW fp32 -----------------
__global__ __launch_bounds__(256) void k_final(const int8_t* __restrict__ x8,
        const int8_t* __restrict__ o2,
        const float* __restrict__ sxp, const float* __restrict__ zxp,
        const float* __restrict__ s2p, const float* __restrict__ z2p,
        const float* __restrict__ sap, const float* __restrict__ zap,
        float* __restrict__ out) {
    __shared__ __align__(16) int8_t ta[128 * 260 + 16];  // row stride 260: conflict-free
    __shared__ __align__(16) int8_t tb[128 * 260 + 16];
    const int tid = threadIdx.x;
    const int p0 = blockIdx.x * 128;
    const uint32_t* xa = (const uint32_t*)(x8 + (size_t)p0 * 256);
    const uint32_t* xb = (const uint32_t*)(o2 + (size_t)p0 * 256);
    uint32_t* la = (uint32_t*)ta;
    uint32_t* lb = (uint32_t*)tb;
#pragma unroll
    for (int k = 0; k < 32; ++k) {      // 128 pos x 256 B = 8192 dwords each
        int d = tid + k * 256;
        int idx = (d >> 6) * 65 + (d & 63);
        la[idx] = xa[d];
        lb[idx] = xb[d];
    }
    __syncthreads();
    const float ra = sxp[0] / sap[0];
    const float rb = s2p[0] / sap[0];
    const float zx = zxp[0];
    const float z2 = z2p[0];
    const float za = zap[0];
#pragma unroll 4
    for (int it = 0; it < 128; ++it) {
        int idx = tid + it * 256;
        int oc = idx >> 7;
        int pp = idx & 127;
        float av = (float)((int)ta[pp * 260 + oc] + 128) - zx;
        float bv = (float)((int)tb[pp * 260 + oc] + 128) - z2;
        float y = ra * av + rb * bv;
        float q = rintf(y) + za;
        q = fminf(fmaxf(q, 0.0f), 255.0f);
        int pz = p0 + pp;
        int n = pz / HWP, hh = pz % HWP;
        out[((size_t)(n * 256 + oc)) * HWP + hh] = q;
    }
}

extern "C" void kernel_launch(void* const* d_in, const int* in_sizes, int n_in,
                              void* d_out, int out_size, void* d_ws, size_t ws_size,
                              hipStream_t stream) {
    (void)in_sizes; (void)n_in; (void)out_size; (void)ws_size;
    const float* x    = (const float*)d_in[0];
    const float* w1   = (const float*)d_in[1];
    const float* w2   = (const float*)d_in[2];
    const float* s_x  = (const float*)d_in[3];
    const float* z_x  = (const float*)d_in[4];
    const float* s_w1 = (const float*)d_in[5];
    const float* s_c1 = (const float*)d_in[6];
    const float* z_c1 = (const float*)d_in[7];
    const float* s_w2 = (const float*)d_in[8];
    const float* s_c2 = (const float*)d_in[9];
    const float* z_c2 = (const float*)d_in[10];
    const float* s_ad = (const float*)d_in[11];
    const float* z_ad = (const float*)d_in[12];
    float* out = (float*)d_out;

    // workspace layout (needs ~39.72 MB)
    int8_t* ws   = (int8_t*)d_ws;
    int8_t* x8   = ws;                       // 12,845,056  (NHWC i8 of x-128)
    int8_t* o1   = ws + 12845056;            // 12,845,056  (conv1 out, q-128)
    int8_t* o2   = ws + 25690112;            // 12,845,056  (conv2 out, q-128)
    int8_t* w8a  = ws + 38535168;            // 589,824     (w1 frag-major)
    int8_t* w8b  = ws + 39124992;            // 589,824     (w2 frag-major)
    int*    wsum1 = (int*)(ws + 39714816);   // 1024
    int*    wsum2 = (int*)(ws + 39715840);   // 1024
    int8_t* fill1 = ws + 39716864;           // 64 (pad bytes z_x-128 = 0)
    int8_t* fill2 = ws + 39716928;           // 64 (pad bytes z_c1-128 = -8)

    k_x_to_nhwc<<<1792, 256, 0, stream>>>(x, x8);
    k_w_prep<<<576, 256, 0, stream>>>(w1, w8a);
    k_w_prep<<<576, 256, 0, stream>>>(w2, w8b);
    k_wsum_fill<<<256, 256, 0, stream>>>(w1, wsum1, fill1, z_x);
    k_wsum_fill<<<256, 256, 0, stream>>>(w2, wsum2, fill2, z_c1);
    k_qconv<<<784, 256, 0, stream>>>(x8, w8a, wsum1, fill1, s_x, s_w1, s_c1, z_x, z_c1, o1);
    k_qconv<<<784, 256, 0, stream>>>(o1, w8b, wsum2, fill2, s_c1, s_w2, s_c2, z_c1, z_c2, o2);
    k_final<<<392, 256, 0, stream>>>(x8, o2, s_x, z_x, s_c2, z_c2, s_ad, z_ad, out);
}

// Round 2
// 225.500 us; speedup vs baseline: 1.1502x; 1.1502x over previous
//
#include <hip/hip_runtime.h>
#include <stdint.h>

#define HWP 784      // 28*28
#define NPOS 50176   // 64*784 positions

typedef int int4v  __attribute__((ext_vector_type(4)));
typedef int int16v __attribute__((ext_vector_type(16)));
using as1_cv = const __attribute__((address_space(1))) void;
using as3_v  = __attribute__((address_space(3))) void;

// ---------------- kernel 1: x NCHW fp32 -> x8 NHWC int8 (value - 128) ----------------
__global__ __launch_bounds__(256) void k_x_to_nhwc(const float* __restrict__ x,
                                                   int8_t* __restrict__ x8) {
    __shared__ __align__(16) int8_t tile[64][116];  // [c][hw], padded row -> conflict-free
    int b = blockIdx.x;                 // b = n*28 + hwt*4 + ct
    int ct = b & 3;
    int hwt = (b >> 2) % 7;
    int n = b / 28;
    int c0 = ct * 64, hw0 = hwt * 112;
    int tid = threadIdx.x;
#pragma unroll
    for (int k = 0; k < 28; ++k) {      // 64c x 112hw = 7168 elems
        int e = tid + k * 256;
        int c = e / 112, hh = e % 112;
        float v = x[((size_t)(n * 256 + c0 + c)) * HWP + hw0 + hh];
        tile[c][hh] = (int8_t)((int)v - 128);
    }
    __syncthreads();
    int cc = tid & 63;
    int pb = tid >> 6;
#pragma unroll
    for (int j = 0; j < 28; ++j) {
        int pi = pb + j * 4;
        x8[((size_t)(n * HWP + hw0 + pi)) * 256 + c0 + cc] = tile[cc][pi];
    }
}

// ---------------- kernel 2: weights OIHW fp32 -> fragment-major int8 + per-oc sums --
// layout byte index: ((((tap*4+kb)*2+s)*8 + g)*64 + l)*16 + j
//   oc = g*32 + (l&31); ic = kb*64 + s*32 + (l>>5)*16 + j
// One block per oc: reads 2304 consecutive floats (coalesced), fuses wsum reduction.
__global__ __launch_bounds__(256) void k_w_prep(const float* __restrict__ w,
                                                int8_t* __restrict__ w8,
                                                int* __restrict__ wsum) {
    __shared__ int red[256];
    const int oc = blockIdx.x;
    const int t = threadIdx.x;          // t = ic
    const float* src = w + (size_t)oc * 2304 + (size_t)t * 9;
    const int g = oc >> 5;
    const int l = ((t >> 4) & 1) * 32 + (oc & 31);
    const int j = t & 15;
    const int s2 = (t >> 5) & 1;
    const int kb = t >> 6;
    int acc = 0;
#pragma unroll
    for (int tap = 0; tap < 9; ++tap) {
        int wv = (int)src[tap];
        acc += wv;
        int oo = ((((tap * 4 + kb) * 2 + s2) * 8 + g) * 64 + l) * 16 + j;
        w8[oo] = (int8_t)wv;
    }
    red[t] = acc;
    __syncthreads();
    for (int st = 128; st > 0; st >>= 1) {
        if (t < st) red[t] += red[t + st];
        __syncthreads();
    }
    if (t == 0) wsum[oc] = red[0];
}

// ---------------- kernel 3: quantized 3x3 conv, single-barrier implicit GEMM --------
// Block: 64 positions x 256 oc.  Whole K=2304 A-operand (halo slab, 122 rows x 256 B)
// staged to LDS ONCE via global_load_lds (XOR-16 chunk swizzle at source-address time),
// one __syncthreads, then 288 MFMAs with no further barriers.  Out-of-image taps are
// replaced at fragment-read time with the pad splat (z_in - 128); the epilogue adds
// (128 - z_in) * Wsum[oc] so integer accumulation is exact.
__global__ __launch_bounds__(256) void k_qconv(const int8_t* __restrict__ in8,
        const int8_t* __restrict__ w8, const int* __restrict__ wsum,
        const float* __restrict__ s_in_p, const float* __restrict__ s_w_p,
        const float* __restrict__ s_out_p, const float* __restrict__ z_in_p,
        const float* __restrict__ z_out_p, int8_t* __restrict__ out8) {
    __shared__ __align__(16) int8_t slab[32768];   // 128 rows x 256 B (122 used)
    const int tid = threadIdx.x;
    const int lane = tid & 63;
    const int half = lane >> 5;
    const int wv = tid >> 6;
    const int p0 = blockIdx.x * 64;

    // ---- stage: 2048 16B chunks; slot (q, cslot) holds global chunk (cslot ^ (q&15))
    {
        const int base_byte = (p0 - 29) * 256;
        const int maxb = NPOS * 256 - 16;
#pragma unroll
        for (int i = 0; i < 8; ++i) {
            int chunkid = tid + i * 256;
            int q = chunkid >> 4;
            int cslot = chunkid & 15;
            int gchunk = cslot ^ (q & 15);
            int src = base_byte + q * 256 + gchunk * 16;
            src = src < 0 ? 0 : (src > maxb ? maxb : src);
            __builtin_amdgcn_global_load_lds((as1_cv*)(in8 + src),
                                             (as3_v*)&slab[chunkid * 16], 16, 0, 0);
        }
    }

    // per-lane row geometry for the 2 m-tiles
    int rowpos[2], ph[2], pw[2];
#pragma unroll
    for (int mt = 0; mt < 2; ++mt) {
        rowpos[mt] = mt * 32 + (lane & 31);
        int p = p0 + rowpos[mt];
        int hw = p % HWP;
        ph[mt] = hw / 28;
        pw[mt] = hw % 28;
    }

    // pad splat = z_in - 128 replicated to 16 bytes
    const int zi = (int)z_in_p[0] - 128;
    const int spl = (zi & 0xff) * 0x01010101;
    int4v pad;
    pad[0] = spl; pad[1] = spl; pad[2] = spl; pad[3] = spl;

    int16v acc[2][2];
#pragma unroll
    for (int mt = 0; mt < 2; ++mt)
#pragma unroll
        for (int nt = 0; nt < 2; ++nt)
#pragma unroll
            for (int r = 0; r < 16; ++r) acc[mt][nt][r] = 0;

    const int8_t* wlane = w8 + ((size_t)(wv * 2 * 64 + lane)) * 16;

    __syncthreads();   // the ONLY barrier

#pragma unroll 1
    for (int kb = 0; kb < 4; ++kb) {
#pragma unroll
        for (int tap = 0; tap < 9; ++tap) {
            const int dh = tap / 3 - 1;
            const int dw = tap % 3 - 1;
            const int8_t* wb = wlane + (size_t)(tap * 4 + kb) * 16384;
            int4v b0[2], b1[2];
#pragma unroll
            for (int nt = 0; nt < 2; ++nt) {
                b0[nt] = *(const int4v*)(wb + nt * 1024);          // k-sub 0
                b1[nt] = *(const int4v*)(wb + 8192 + nt * 1024);   // k-sub 1
            }
            int4v a0[2], a1[2];
#pragma unroll
            for (int mt = 0; mt < 2; ++mt) {
                int q = rowpos[mt] + dh * 28 + dw + 29;
                int sw = q & 15;
                int base = q * 256;
                int4v v0 = *(const int4v*)&slab[base + ((kb * 4 + half) ^ sw) * 16];
                int4v v1 = *(const int4v*)&slab[base + ((kb * 4 + 2 + half) ^ sw) * 16];
                bool ok = ((unsigned)(ph[mt] + dh) < 28u) & ((unsigned)(pw[mt] + dw) < 28u);
                a0[mt] = ok ? v0 : pad;
                a1[mt] = ok ? v1 : pad;
            }
#pragma unroll
            for (int mt = 0; mt < 2; ++mt)
#pragma unroll
                for (int nt = 0; nt < 2; ++nt) {
                    acc[mt][nt] = __builtin_amdgcn_mfma_i32_32x32x32_i8(a0[mt], b0[nt], acc[mt][nt], 0, 0, 0);
                    acc[mt][nt] = __builtin_amdgcn_mfma_i32_32x32x32_i8(a1[mt], b1[nt], acc[mt][nt], 0, 0, 0);
                }
        }
    }

    // epilogue: requantize.  q = clip(rint(M*acc) + z_out, 0, 255); store q-128.
    const float Mf = s_in_p[0] * s_w_p[0] / s_out_p[0];
    const float zof = z_out_p[0];
    const int zoffi = 128 - (int)z_in_p[0];
#pragma unroll
    for (int nt = 0; nt < 2; ++nt) {
        int oc = wv * 64 + nt * 32 + (lane & 31);
        int corr = zoffi * wsum[oc];
#pragma unroll
        for (int mt = 0; mt < 2; ++mt) {
#pragma unroll
            for (int r = 0; r < 16; ++r) {
                int row = (r & 3) + 8 * (r >> 2) + 4 * half;   // 32x32 C/D layout
                int pos = p0 + mt * 32 + row;
                float q = rintf(Mf * (float)(acc[mt][nt][r] + corr)) + zof;
                q = fminf(fmaxf(q, 0.0f), 255.0f);
                out8[(size_t)pos * 256 + oc] = (int8_t)((int)q - 128);
            }
        }
    }
}

// ---------------- kernel 4: residual qadd, NHWC i8 x2 -> NCHW fp32 -----------------
__global__ __launch_bounds__(256) void k_final(const int8_t* __restrict__ x8,
        const int8_t* __restrict__ o2,
        const float* __restrict__ sxp, const float* __restrict__ zxp,
        const float* __restrict__ s2p, const float* __restrict__ z2p,
        const float* __restrict__ sap, const float* __restrict__ zap,
        float* __restrict__ out) {
    __shared__ __align__(16) int8_t ta[128 * 260 + 16];  // row stride 260: conflict-free
    __shared__ __align__(16) int8_t tb[128 * 260 + 16];
    const int tid = threadIdx.x;
    const int p0 = blockIdx.x * 128;
    const uint32_t* xa = (const uint32_t*)(x8 + (size_t)p0 * 256);
    const uint32_t* xb = (const uint32_t*)(o2 + (size_t)p0 * 256);
    uint32_t* la = (uint32_t*)ta;
    uint32_t* lb = (uint32_t*)tb;
#pragma unroll
    for (int k = 0; k < 32; ++k) {      // 128 pos x 256 B = 8192 dwords each
        int d = tid + k * 256;
        int idx = (d >> 6) * 65 + (d & 63);
        la[idx] = xa[d];
        lb[idx] = xb[d];
    }
    __syncthreads();
    const float ra = sxp[0] / sap[0];
    const float rb = s2p[0] / sap[0];
    const float zx = zxp[0];
    const float z2 = z2p[0];
    const float za = zap[0];
#pragma unroll 4
    for (int it = 0; it < 128; ++it) {
        int idx = tid + it * 256;
        int oc = idx >> 7;
        int pp = idx & 127;
        float av = (float)((int)ta[pp * 260 + oc] + 128) - zx;
        float bv = (float)((int)tb[pp * 260 + oc] + 128) - z2;
        float y = ra * av + rb * bv;
        float q = rintf(y) + za;
        q = fminf(fmaxf(q, 0.0f), 255.0f);
        int pz = p0 + pp;
        int n = pz / HWP, hh = pz % HWP;
        out[((size_t)(n * 256 + oc)) * HWP + hh] = q;
    }
}

extern "C" void kernel_launch(void* const* d_in, const int* in_sizes, int n_in,
                              void* d_out, int out_size, void* d_ws, size_t ws_size,
                              hipStream_t stream) {
    (void)in_sizes; (void)n_in; (void)out_size; (void)ws_size;
    const float* x    = (const float*)d_in[0];
    const float* w1   = (const float*)d_in[1];
    const float* w2   = (const float*)d_in[2];
    const float* s_x  = (const float*)d_in[3];
    const float* z_x  = (const float*)d_in[4];
    const float* s_w1 = (const float*)d_in[5];
    const float* s_c1 = (const float*)d_in[6];
    const float* z_c1 = (const float*)d_in[7];
    const float* s_w2 = (const float*)d_in[8];
    const float* s_c2 = (const float*)d_in[9];
    const float* z_c2 = (const float*)d_in[10];
    const float* s_ad = (const float*)d_in[11];
    const float* z_ad = (const float*)d_in[12];
    float* out = (float*)d_out;

    // workspace layout (needs ~39.72 MB)
    int8_t* ws   = (int8_t*)d_ws;
    int8_t* x8   = ws;                       // 12,845,056  (NHWC i8 of x-128)
    int8_t* o1   = ws + 12845056;            // 12,845,056  (conv1 out, q-128)
    int8_t* o2   = ws + 25690112;            // 12,845,056  (conv2 out, q-128)
    int8_t* w8a  = ws + 38535168;            // 589,824     (w1 frag-major)
    int8_t* w8b  = ws + 39124992;            // 589,824     (w2 frag-major)
    int*    wsum1 = (int*)(ws + 39714816);   // 1024
    int*    wsum2 = (int*)(ws + 39715840);   // 1024

    k_x_to_nhwc<<<1792, 256, 0, stream>>>(x, x8);
    k_w_prep<<<256, 256, 0, stream>>>(w1, w8a, wsum1);
    k_w_prep<<<256, 256, 0, stream>>>(w2, w8b, wsum2);
    k_qconv<<<784, 256, 0, stream>>>(x8, w8a, wsum1, s_x, s_w1, s_c1, z_x, z_c1, o1);
    k_qconv<<<784, 256, 0, stream>>>(o1, w8b, wsum2, s_c1, s_w2, s_c2, z_c1, z_c2, o2);
    k_final<<<392, 256, 0, stream>>>(x8, o2, s_x, z_x, s_c2, z_c2, s_ad, z_ad, out);
}

// Round 3
// 216.885 us; speedup vs baseline: 1.1958x; 1.0397x over previous
//
#include <hip/hip_runtime.h>
#include <stdint.h>

#define HWP 784      // 28*28
#define NPOS 50176   // 64*784 positions

typedef int int4v  __attribute__((ext_vector_type(4)));
typedef int int16v __attribute__((ext_vector_type(16)));
using as1_cv = const __attribute__((address_space(1))) void;
using as3_v  = __attribute__((address_space(3))) void;

// ---------------- kernel 1: x NCHW fp32 -> x8 NHWC int8 (value - 128) ----------------
__global__ __launch_bounds__(256) void k_x_to_nhwc(const float* __restrict__ x,
                                                   int8_t* __restrict__ x8) {
    __shared__ __align__(16) int8_t tile[64][116];  // [c][hw], padded row -> conflict-free
    int b = blockIdx.x;                 // b = n*28 + hwt*4 + ct
    int ct = b & 3;
    int hwt = (b >> 2) % 7;
    int n = b / 28;
    int c0 = ct * 64, hw0 = hwt * 112;
    int tid = threadIdx.x;
#pragma unroll
    for (int k = 0; k < 28; ++k) {      // 64c x 112hw = 7168 elems
        int e = tid + k * 256;
        int c = e / 112, hh = e % 112;
        float v = x[((size_t)(n * 256 + c0 + c)) * HWP + hw0 + hh];
        tile[c][hh] = (int8_t)((int)v - 128);
    }
    __syncthreads();
    int cc = tid & 63;
    int pb = tid >> 6;
#pragma unroll
    for (int j = 0; j < 28; ++j) {
        int pi = pb + j * 4;
        x8[((size_t)(n * HWP + hw0 + pi)) * 256 + c0 + cc] = tile[cc][pi];
    }
}

// ---------------- kernel 2: weights OIHW fp32 -> fragment-major int8 + per-oc sums --
// layout byte index: ((((tap*4+kb)*2+s)*8 + gg)*64 + l)*16 + j
//   oc = gg*32 + (l&31); ic = kb*64 + s*32 + (l>>5)*16 + j
__global__ __launch_bounds__(256) void k_w_prep(const float* __restrict__ w,
                                                int8_t* __restrict__ w8,
                                                int* __restrict__ wsum) {
    __shared__ int red[256];
    const int oc = blockIdx.x;
    const int t = threadIdx.x;          // t = ic
    const float* src = w + (size_t)oc * 2304 + (size_t)t * 9;
    const int g = oc >> 5;
    const int l = ((t >> 4) & 1) * 32 + (oc & 31);
    const int j = t & 15;
    const int s2 = (t >> 5) & 1;
    const int kb = t >> 6;
    int acc = 0;
#pragma unroll
    for (int tap = 0; tap < 9; ++tap) {
        int wv = (int)src[tap];
        acc += wv;
        int oo = ((((tap * 4 + kb) * 2 + s2) * 8 + g) * 64 + l) * 16 + j;
        w8[oo] = (int8_t)wv;
    }
    red[t] = acc;
    __syncthreads();
    for (int st = 128; st > 0; st >>= 1) {
        if (t < st) red[t] += red[t + st];
        __syncthreads();
    }
    if (t == 0) wsum[oc] = red[0];
}

// ---------------- kernel 3: quantized 3x3 conv, 256pos x 64oc blocks ----------------
// All 4 waves share the SAME 64-oc B-slice (block-uniform B addresses -> L1 broadcast,
// 4x less L2 B-traffic).  A-operand: 320-row halo slab (80 KB LDS) staged ONCE via
// global_load_lds with XOR-16 chunk swizzle; one barrier; 288 MFMAs/wave with B
// prefetched one K-step ahead.  FUSED variant folds the residual qadd + NCHW fp32
// store (via conflict-free LDS transpose) into the epilogue.
template<bool FUSED>
__global__ __launch_bounds__(256) void k_qconv_t(const int8_t* __restrict__ in8,
        const int8_t* __restrict__ w8, const int* __restrict__ wsum,
        const float* __restrict__ s_in_p, const float* __restrict__ s_w_p,
        const float* __restrict__ s_out_p, const float* __restrict__ z_in_p,
        const float* __restrict__ z_out_p, int8_t* __restrict__ out8,
        const int8_t* __restrict__ x8, const float* __restrict__ sxp,
        const float* __restrict__ zxp, const float* __restrict__ sap,
        const float* __restrict__ zap, float* __restrict__ outf) {
    __shared__ __align__(16) int8_t slab[81920];   // 320 rows x 256 B
    const int tid = threadIdx.x;
    const int lane = tid & 63;
    const int half = lane >> 5;
    const int wv = tid >> 6;
    const int p0 = blockIdx.x * 256;   // 196 position tiles
    const int g = blockIdx.y;          // 4 oc-groups of 64

    // ---- stage: 5120 16B chunks; slot (q, cslot) holds global chunk (cslot ^ (q&15))
    {
        const int base_byte = (p0 - 29) * 256;
        const int maxb = NPOS * 256 - 16;
#pragma unroll
        for (int i = 0; i < 20; ++i) {
            int chunkid = tid + i * 256;
            int q = chunkid >> 4;
            int cslot = chunkid & 15;
            int gchunk = cslot ^ (q & 15);
            int src = base_byte + q * 256 + gchunk * 16;
            src = src < 0 ? 0 : (src > maxb ? maxb : src);
            __builtin_amdgcn_global_load_lds((as1_cv*)(in8 + src),
                                             (as3_v*)&slab[chunkid * 16], 16, 0, 0);
        }
    }

    // per-lane row geometry for the 2 m-tiles (wave wv owns positions [wv*64, wv*64+64))
    int rowpos[2], ph[2], pw[2];
#pragma unroll
    for (int mt = 0; mt < 2; ++mt) {
        rowpos[mt] = wv * 64 + mt * 32 + (lane & 31);
        int p = p0 + rowpos[mt];
        int hw = p % HWP;
        ph[mt] = hw / 28;
        pw[mt] = hw % 28;
    }

    // pad splat = z_in - 128 replicated to 16 bytes
    const int zi = (int)z_in_p[0] - 128;
    const int spl = (zi & 0xff) * 0x01010101;
    int4v pad;
    pad[0] = spl; pad[1] = spl; pad[2] = spl; pad[3] = spl;

    int16v acc[2][2];
#pragma unroll
    for (int mt = 0; mt < 2; ++mt)
#pragma unroll
        for (int nt = 0; nt < 2; ++nt)
#pragma unroll
            for (int r = 0; r < 16; ++r) acc[mt][nt][r] = 0;

    // B base: block-uniform oc-group g; gg = g*2 + nt
    const int8_t* wlane = w8 + g * 2048 + lane * 16;
    auto loadB = [&](int u, int4v* b0, int4v* b1) {
        const int8_t* wb = wlane + (size_t)u * 16384;
        b0[0] = *(const int4v*)(wb);
        b0[1] = *(const int4v*)(wb + 1024);
        b1[0] = *(const int4v*)(wb + 8192);
        b1[1] = *(const int4v*)(wb + 9216);
    };

    int4v cb0[2], cb1[2];
    loadB(0, cb0, cb1);

    __syncthreads();   // the only barrier in the K-loop

#pragma unroll 1
    for (int tap = 0; tap < 9; ++tap) {
        const int dh = tap / 3 - 1;
        const int dw = tap % 3 - 1;
        int qbase[2];
        bool okm[2];
#pragma unroll
        for (int mt = 0; mt < 2; ++mt) {
            qbase[mt] = rowpos[mt] + dh * 28 + dw + 29;
            okm[mt] = ((unsigned)(ph[mt] + dh) < 28u) & ((unsigned)(pw[mt] + dw) < 28u);
        }
#pragma unroll
        for (int kb = 0; kb < 4; ++kb) {
            const int u = tap * 4 + kb;
            int4v nb0[2], nb1[2];
            int un = u < 35 ? u + 1 : 35;      // branchless prefetch (step 35 reloads itself)
            loadB(un, nb0, nb1);
            int4v a0[2], a1[2];
#pragma unroll
            for (int mt = 0; mt < 2; ++mt) {
                int q = qbase[mt];
                int sw = q & 15;
                int base = q * 256;
                int4v v0 = *(const int4v*)&slab[base + ((kb * 4 + half) ^ sw) * 16];
                int4v v1 = *(const int4v*)&slab[base + ((kb * 4 + 2 + half) ^ sw) * 16];
                a0[mt] = okm[mt] ? v0 : pad;
                a1[mt] = okm[mt] ? v1 : pad;
            }
#pragma unroll
            for (int mt = 0; mt < 2; ++mt)
#pragma unroll
                for (int nt = 0; nt < 2; ++nt) {
                    acc[mt][nt] = __builtin_amdgcn_mfma_i32_32x32x32_i8(a0[mt], cb0[nt], acc[mt][nt], 0, 0, 0);
                    acc[mt][nt] = __builtin_amdgcn_mfma_i32_32x32x32_i8(a1[mt], cb1[nt], acc[mt][nt], 0, 0, 0);
                }
#pragma unroll
            for (int nt = 0; nt < 2; ++nt) { cb0[nt] = nb0[nt]; cb1[nt] = nb1[nt]; }
        }
    }

    // ---- epilogue: requantize (exact integer): q = clip(rint(M*acc)+z_out, 0, 255)
    const float Mf = s_in_p[0] * s_w_p[0] / s_out_p[0];
    const float zof = z_out_p[0];
    const int zoffi = 128 - (int)z_in_p[0];

    if (!FUSED) {
#pragma unroll
        for (int nt = 0; nt < 2; ++nt) {
            int oc = g * 64 + nt * 32 + (lane & 31);
            int corr = zoffi * wsum[oc];
#pragma unroll
            for (int mt = 0; mt < 2; ++mt) {
#pragma unroll
                for (int r = 0; r < 16; ++r) {
                    int row = (r & 3) + 8 * (r >> 2) + 4 * half;   // 32x32 C/D layout
                    int pos = p0 + wv * 64 + mt * 32 + row;
                    float q = rintf(Mf * (float)(acc[mt][nt][r] + corr)) + zof;
                    q = fminf(fmaxf(q, 0.0f), 255.0f);
                    out8[(size_t)pos * 256 + oc] = (int8_t)((int)q - 128);
                }
            }
        }
    } else {
        // fused residual qadd: out = clip(rint(ra*(qx-zx) + rb*(q2-z2)) + za, 0, 255)
        const float ra = sxp[0] / sap[0];
        const float rb = s_out_p[0] / sap[0];
        const float zx = zxp[0];
        const float z2 = z_out_p[0];
        const float za = zap[0];
        __syncthreads();                                // slab A-data now dead everywhere
        float* tp = (float*)(slab + wv * 16640);        // 64 pos x 64 oc, stride 65 floats
#pragma unroll
        for (int nt = 0; nt < 2; ++nt) {
            int ocl = nt * 32 + (lane & 31);
            int oc = g * 64 + ocl;
            int corr = zoffi * wsum[oc];
#pragma unroll
            for (int mt = 0; mt < 2; ++mt) {
#pragma unroll
                for (int r = 0; r < 16; ++r) {
                    int row = (r & 3) + 8 * (r >> 2) + 4 * half;
                    int pl = mt * 32 + row;                       // local pos in [0,64)
                    int pos = p0 + wv * 64 + pl;
                    float q2 = rintf(Mf * (float)(acc[mt][nt][r] + corr)) + zof;
                    q2 = fminf(fmaxf(q2, 0.0f), 255.0f);
                    float av = (float)((int)x8[(size_t)pos * 256 + oc] + 128) - zx;
                    float bv = q2 - z2;
                    float y = ra * av + rb * bv;
                    float qf = rintf(y) + za;
                    qf = fminf(fmaxf(qf, 0.0f), 255.0f);
                    tp[pl * 65 + ocl] = qf;
                }
            }
        }
        // wave-local transpose read + coalesced NCHW fp32 store
        int p = p0 + wv * 64 + lane;
        int n = p / HWP;
        int hw = p % HWP;
        float* obase = outf + (size_t)n * (256 * HWP) + hw + (size_t)(g * 64) * HWP;
#pragma unroll 8
        for (int oc = 0; oc < 64; ++oc) {
            obase[(size_t)oc * HWP] = tp[lane * 65 + oc];
        }
    }
}

extern "C" void kernel_launch(void* const* d_in, const int* in_sizes, int n_in,
                              void* d_out, int out_size, void* d_ws, size_t ws_size,
                              hipStream_t stream) {
    (void)in_sizes; (void)n_in; (void)out_size; (void)ws_size;
    const float* x    = (const float*)d_in[0];
    const float* w1   = (const float*)d_in[1];
    const float* w2   = (const float*)d_in[2];
    const float* s_x  = (const float*)d_in[3];
    const float* z_x  = (const float*)d_in[4];
    const float* s_w1 = (const float*)d_in[5];
    const float* s_c1 = (const float*)d_in[6];
    const float* z_c1 = (const float*)d_in[7];
    const float* s_w2 = (const float*)d_in[8];
    const float* s_c2 = (const float*)d_in[9];
    const float* z_c2 = (const float*)d_in[10];
    const float* s_ad = (const float*)d_in[11];
    const float* z_ad = (const float*)d_in[12];
    float* out = (float*)d_out;

    // workspace layout (~26.9 MB)
    int8_t* ws   = (int8_t*)d_ws;
    int8_t* x8   = ws;                       // 12,845,056  (NHWC i8 of x-128)
    int8_t* o1   = ws + 12845056;            // 12,845,056  (conv1 out, q-128)
    int8_t* w8a  = ws + 25690112;            // 589,824     (w1 frag-major)
    int8_t* w8b  = ws + 26279936;            // 589,824     (w2 frag-major)
    int*    wsum1 = (int*)(ws + 26869760);   // 1024
    int*    wsum2 = (int*)(ws + 26870784);   // 1024

    k_x_to_nhwc<<<1792, 256, 0, stream>>>(x, x8);
    k_w_prep<<<256, 256, 0, stream>>>(w1, w8a, wsum1);
    k_w_prep<<<256, 256, 0, stream>>>(w2, w8b, wsum2);
    k_qconv_t<false><<<dim3(196, 4), 256, 0, stream>>>(x8, w8a, wsum1,
        s_x, s_w1, s_c1, z_x, z_c1, o1,
        nullptr, nullptr, nullptr, nullptr, nullptr, nullptr);
    k_qconv_t<true><<<dim3(196, 4), 256, 0, stream>>>(o1, w8b, wsum2,
        s_c1, s_w2, s_c2, z_c1, z_c2, nullptr,
        x8, s_x, z_x, s_ad, z_ad, out);
}

// Round 6
// 215.874 us; speedup vs baseline: 1.2014x; 1.0047x over previous
//
#include <hip/hip_runtime.h>
#include <stdint.h>

#define HWP 784                // 28*28
#define NPOS 50176             // 64*784 flat positions
#define PLN ((size_t)NPOS * 64)  // plane stride bytes: [g][pos][64ch]

typedef int   int4v   __attribute__((ext_vector_type(4)));
typedef int   int16v  __attribute__((ext_vector_type(16)));
typedef float float4v __attribute__((ext_vector_type(4)));
using as1_cv = const __attribute__((address_space(1))) void;
using as3_v  = __attribute__((address_space(3))) void;

// ---------------- kernel 1: x NCHW fp32 -> plane-blocked i8 (value-128) -------------
// x8 layout: plane g (64 ch) : [pos][64] bytes.  Block = 56 pos x 256 ch (56 | 784 so
// a block never crosses the image boundary).  float4 reads -> pos-packed dwords in LDS
// -> 4x4 byte transpose -> chan-packed dwords -> contiguous dwordx4 plane stores.
__global__ __launch_bounds__(256) void k_nhwc(const float* __restrict__ x,
                                              int8_t* __restrict__ x8) {
    __shared__ int lA[256 * 15];                 // [c][pq] pos-packed, stride 15
    __shared__ __align__(16) int lB[56 * 68];    // [pos][ch-dword 0..63], stride 68 (272B rows)
    const int tid = threadIdx.x;
    const int P0 = blockIdx.x * 56;
    const int n = P0 / HWP;
    const int hw0 = P0 % HWP;
    const float* xb = x + (size_t)n * 256 * HWP + hw0;
#pragma unroll
    for (int k = 0; k < 14; ++k) {               // 3584 float4 chunks
        int e = tid + k * 256;
        int c = e / 14, pq = e % 14;
        float4v v = *(const float4v*)(xb + (size_t)c * HWP + pq * 4);
        int b0 = ((int)v[0] - 128) & 255;
        int b1 = ((int)v[1] - 128) & 255;
        int b2 = ((int)v[2] - 128) & 255;
        int b3 = ((int)v[3] - 128) & 255;
        lA[c * 15 + pq] = b0 | (b1 << 8) | (b2 << 16) | (b3 << 24);
    }
    __syncthreads();
#pragma unroll
    for (int k = 0; k < 4; ++k) {                // 896 4x4 byte-transpose units
        int u = tid + k * 256;
        if (u < 896) {
            int cg = u / 14, pq = u % 14;        // cg = channel-dword 0..63
            int d0 = lA[(cg * 4 + 0) * 15 + pq];
            int d1 = lA[(cg * 4 + 1) * 15 + pq];
            int d2 = lA[(cg * 4 + 2) * 15 + pq];
            int d3 = lA[(cg * 4 + 3) * 15 + pq];
#pragma unroll
            for (int j = 0; j < 4; ++j) {
                int sh = j * 8;
                int o = ((d0 >> sh) & 255) | (((d1 >> sh) & 255) << 8)
                      | (((d2 >> sh) & 255) << 16) | (((d3 >> sh) & 255) << 24);
                lB[(pq * 4 + j) * 68 + cg] = o;
            }
        }
    }
    __syncthreads();
#pragma unroll
    for (int k = 0; k < 4; ++k) {                // 896 16B output chunks
        int ch = tid + k * 256;
        if (ch < 896) {
            int g = ch / 224, rem = ch % 224;
            int pos = rem >> 2, c4 = rem & 3;
            int4v val = *(const int4v*)&lB[pos * 68 + g * 16 + c4 * 4];
            *(int4v*)(x8 + (size_t)g * PLN + (size_t)(P0 + pos) * 64 + c4 * 16) = val;
        }
    }
}

// ---------------- kernel 2: weights OIHW fp32 -> fragment-major int8 + per-oc sums --
// byte index: ((((tap*4+kb)*2+s)*8 + gg)*64 + l)*16 + j
//   oc = gg*32 + (l&31); ic = kb*64 + s*32 + (l>>5)*16 + j
__global__ __launch_bounds__(256) void k_w_prep(const float* __restrict__ w,
                                                int8_t* __restrict__ w8,
                                                int* __restrict__ wsum) {
    __shared__ int red[256];
    const int oc = blockIdx.x;
    const int t = threadIdx.x;          // t = ic
    const float* src = w + (size_t)oc * 2304 + (size_t)t * 9;
    const int g = oc >> 5;
    const int l = ((t >> 4) & 1) * 32 + (oc & 31);
    const int j = t & 15;
    const int s2 = (t >> 5) & 1;
    const int kb = t >> 6;
    int acc = 0;
#pragma unroll
    for (int tap = 0; tap < 9; ++tap) {
        int wv = (int)src[tap];
        acc += wv;
        int oo = ((((tap * 4 + kb) * 2 + s2) * 8 + g) * 64 + l) * 16 + j;
        w8[oo] = (int8_t)wv;
    }
    red[t] = acc;
    __syncthreads();
    for (int st = 128; st > 0; st >>= 1) {
        if (t < st) red[t] += red[t + st];
        __syncthreads();
    }
    if (t == 0) wsum[oc] = red[0];
}

// ---------------- kernel 3: quantized 3x3 conv, 128pos x 64oc blocks ----------------
// Slab: 186 rows x 256B = 46.5 KB LDS -> 3 blocks/CU.  All 4 waves share the block's
// 64-oc B-slice (L1 broadcast).  Grid (392,4): 392%8==0 so all 4 oc-groups of a
// pos-tile land on the same XCD -> slab re-reads hit L2.  One stage + one barrier,
// 144 MFMAs/wave with 1-step B prefetch.  FUSED: residual qadd + NCHW fp32 store.
template<bool FUSED>
__global__ __launch_bounds__(256, 3) void k_qconv_t(const int8_t* __restrict__ in8,
        const int8_t* __restrict__ w8, const int* __restrict__ wsum,
        const float* __restrict__ s_in_p, const float* __restrict__ s_w_p,
        const float* __restrict__ s_out_p, const float* __restrict__ z_in_p,
        const float* __restrict__ z_out_p, int8_t* __restrict__ out8,
        const int8_t* __restrict__ x8, const float* __restrict__ sxp,
        const float* __restrict__ zxp, const float* __restrict__ sap,
        const float* __restrict__ zap, float* __restrict__ outf) {
    __shared__ __align__(16) int8_t slab[47616];   // 186 rows x 256 B
    const int tid = threadIdx.x;
    const int lane = tid & 63;
    const int half = lane >> 5;
    const int wv = tid >> 6;
    const int p0 = blockIdx.x * 128;   // 392 position tiles
    const int g = blockIdx.y;          // 4 oc-groups of 64

    // ---- stage: 2976 16B chunks; slot (q,cs) holds global chunk cs ^ (q&15)
    {
#pragma unroll
        for (int k = 0; k < 12; ++k) {
            int chunkid = tid + k * 256;
            if (chunkid < 2976) {
                int q = chunkid >> 4;
                int cs = chunkid & 15;
                int cg = cs ^ (q & 15);
                int qg = p0 - 29 + q;
                qg = qg < 0 ? 0 : (qg > NPOS - 1 ? NPOS - 1 : qg);
                const int8_t* src = in8 + (size_t)(cg >> 2) * PLN
                                        + (size_t)qg * 64 + (cg & 3) * 16;
                __builtin_amdgcn_global_load_lds((as1_cv*)src,
                                                 (as3_v*)&slab[chunkid * 16], 16, 0, 0);
            }
        }
    }

    const int rowpos = wv * 32 + (lane & 31);   // wave's 32 positions
    const int p = p0 + rowpos;
    const int hwp_ = p % HWP;
    const int ph = hwp_ / 28;
    const int pw = hwp_ % 28;

    // pad splat = z_in - 128 replicated to 16 bytes
    const int zi = (int)z_in_p[0] - 128;
    const int spl = (zi & 0xff) * 0x01010101;
    int4v pad;
    pad[0] = spl; pad[1] = spl; pad[2] = spl; pad[3] = spl;

    int16v acc[2];
#pragma unroll
    for (int nt = 0; nt < 2; ++nt)
#pragma unroll
        for (int r = 0; r < 16; ++r) acc[nt][r] = 0;

    const int8_t* wlane = w8 + g * 2048 + lane * 16;
    auto loadB = [&](int u, int4v* b0, int4v* b1) {
        const int8_t* wb = wlane + (size_t)u * 16384;
        b0[0] = *(const int4v*)(wb);
        b0[1] = *(const int4v*)(wb + 1024);
        b1[0] = *(const int4v*)(wb + 8192);
        b1[1] = *(const int4v*)(wb + 9216);
    };
    int4v cb0[2], cb1[2];
    loadB(0, cb0, cb1);

    __syncthreads();   // the only barrier before the K-loop

#pragma unroll 1
    for (int tap = 0; tap < 9; ++tap) {
        const int dh = tap / 3 - 1;
        const int dw = tap % 3 - 1;
        const int qrow = rowpos + dh * 28 + dw + 29;          // LDS row 0..185
        const bool ok = ((unsigned)(ph + dh) < 28u) & ((unsigned)(pw + dw) < 28u);
        const int sw = qrow & 15;
        const int base = qrow * 256;
#pragma unroll
        for (int kb = 0; kb < 4; ++kb) {
            const int u = tap * 4 + kb;
            int4v nb0[2], nb1[2];
            int un = u < 35 ? u + 1 : 35;
            loadB(un, nb0, nb1);
            int4v a0 = *(const int4v*)&slab[base + ((kb * 4 + half) ^ sw) * 16];
            int4v a1 = *(const int4v*)&slab[base + ((kb * 4 + 2 + half) ^ sw) * 16];
            a0 = ok ? a0 : pad;
            a1 = ok ? a1 : pad;
#pragma unroll
            for (int nt = 0; nt < 2; ++nt) {
                acc[nt] = __builtin_amdgcn_mfma_i32_32x32x32_i8(a0, cb0[nt], acc[nt], 0, 0, 0);
                acc[nt] = __builtin_amdgcn_mfma_i32_32x32x32_i8(a1, cb1[nt], acc[nt], 0, 0, 0);
            }
#pragma unroll
            for (int nt = 0; nt < 2; ++nt) { cb0[nt] = nb0[nt]; cb1[nt] = nb1[nt]; }
        }
    }

    // ---- epilogue: requant q = clip(rint(M*acc)+z_out, 0, 255) (exact integer path)
    const float Mf = s_in_p[0] * s_w_p[0] / s_out_p[0];
    const float zof = z_out_p[0];
    const int zoffi = 128 - (int)z_in_p[0];

    if (!FUSED) {
        int8_t* o8p = out8 + (size_t)g * PLN;
#pragma unroll
        for (int nt = 0; nt < 2; ++nt) {
            int oc = g * 64 + nt * 32 + (lane & 31);
            int corr = zoffi * wsum[oc];
#pragma unroll
            for (int r = 0; r < 16; ++r) {
                int row = (r & 3) + 8 * (r >> 2) + 4 * half;   // 32x32 C/D layout
                int pos = p0 + wv * 32 + row;
                float q = rintf(Mf * (float)(acc[nt][r] + corr)) + zof;
                q = fminf(fmaxf(q, 0.0f), 255.0f);
                o8p[(size_t)pos * 64 + nt * 32 + (lane & 31)] = (int8_t)((int)q - 128);
            }
        }
    } else {
        // fused residual qadd: out = clip(rint(ra*(qx-zx) + rb*(q2-z2)) + za, 0, 255)
        const float ra = sxp[0] / sap[0];
        const float rb = s_out_p[0] / sap[0];
        const float zx = zxp[0];
        const float z2 = z_out_p[0];
        const float za = zap[0];
        __syncthreads();                        // slab A-data dead in all waves
        float* tp = (float*)slab + wv * 2080;   // 32 pos x 64 oc fp32, stride 65
#pragma unroll
        for (int nt = 0; nt < 2; ++nt) {
            int oc = g * 64 + nt * 32 + (lane & 31);
            int corr = zoffi * wsum[oc];
#pragma unroll
            for (int r = 0; r < 16; ++r) {
                int pl = (r & 3) + 8 * (r >> 2) + 4 * half;
                float q2 = rintf(Mf * (float)(acc[nt][r] + corr)) + zof;
                q2 = fminf(fmaxf(q2, 0.0f), 255.0f);
                tp[pl * 65 + nt * 32 + (lane & 31)] = q2;
            }
        }
        // same-wave readback (DS is in-order per wave): lane = (pos, oc-half)
        const int pl = lane & 31;
        const int hh = half;
        const int pglob = p0 + wv * 32 + pl;
        const int8_t* x8p = x8 + (size_t)g * PLN + (size_t)pglob * 64 + hh * 32;
        int4v r0 = *(const int4v*)x8p;          // 32 residual bytes, coalesced
        int4v r1 = *(const int4v*)(x8p + 16);
        int xb[8];
        xb[0] = r0[0]; xb[1] = r0[1]; xb[2] = r0[2]; xb[3] = r0[3];
        xb[4] = r1[0]; xb[5] = r1[1]; xb[6] = r1[2]; xb[7] = r1[3];
        const int n = pglob / HWP;
        const int hwo = pglob % HWP;
        float* obase = outf + ((size_t)(n * 256 + g * 64 + hh * 32)) * HWP + hwo;
#pragma unroll
        for (int j = 0; j < 32; ++j) {
            int bv = (xb[j >> 2] >> ((j & 3) * 8)) & 255;
            int xval = (int)(int8_t)bv + 128;   // stored value-128 -> q in [0,255]
            float q2 = tp[pl * 65 + hh * 32 + j];
            float y = ra * ((float)xval - zx) + rb * (q2 - z2);
            float qf = rintf(y) + za;
            qf = fminf(fmaxf(qf, 0.0f), 255.0f);
            obase[(size_t)j * HWP] = qf;
        }
    }
}

extern "C" void kernel_launch(void* const* d_in, const int* in_sizes, int n_in,
                              void* d_out, int out_size, void* d_ws, size_t ws_size,
                              hipStream_t stream) {
    (void)in_sizes; (void)n_in; (void)out_size; (void)ws_size;
    const float* x    = (const float*)d_in[0];
    const float* w1   = (const float*)d_in[1];
    const float* w2   = (const float*)d_in[2];
    const float* s_x  = (const float*)d_in[3];
    const float* z_x  = (const float*)d_in[4];
    const float* s_w1 = (const float*)d_in[5];
    const float* s_c1 = (const float*)d_in[6];
    const float* z_c1 = (const float*)d_in[7];
    const float* s_w2 = (const float*)d_in[8];
    const float* s_c2 = (const float*)d_in[9];
    const float* z_c2 = (const float*)d_in[10];
    const float* s_ad = (const float*)d_in[11];
    const float* z_ad = (const float*)d_in[12];
    float* out = (float*)d_out;

    // workspace layout (~26.9 MB)
    int8_t* ws    = (int8_t*)d_ws;
    int8_t* x8    = ws;                       // 4 planes x 3,211,264 = 12,845,056
    int8_t* o1    = ws + 12845056;            // 12,845,056 (conv1 out, plane-blocked)
    int8_t* w8a   = ws + 25690112;            // 589,824
    int8_t* w8b   = ws + 26279936;            // 589,824
    int*    wsum1 = (int*)(ws + 26869760);    // 1024
    int*    wsum2 = (int*)(ws + 26870784);    // 1024

    k_nhwc<<<896, 256, 0, stream>>>(x, x8);
    k_w_prep<<<256, 256, 0, stream>>>(w1, w8a, wsum1);
    k_w_prep<<<256, 256, 0, stream>>>(w2, w8b, wsum2);
    k_qconv_t<false><<<dim3(392, 4), 256, 0, stream>>>(x8, w8a, wsum1,
        s_x, s_w1, s_c1, z_x, z_c1, o1,
        nullptr, nullptr, nullptr, nullptr, nullptr, nullptr);
    k_qconv_t<true><<<dim3(392, 4), 256, 0, stream>>>(o1, w8b, wsum2,
        s_c1, s_w2, s_c2, z_c1, z_c2, nullptr,
        x8, s_x, z_x, s_ad, z_ad, out);
}